// Round 2
// baseline (67.137 us; speedup 1.0000x reference)
//
#include <hip/hip_runtime.h>

// ParabolicPool2D: out[b,c,i,j] = max_{p,q} f[b,c,2i+p,2j+q] - z[p,q]*t[c]
// z = [[1,.5,1],[.5,0,.5],[1,.5,1]]  -> corners: -t, edges: -0.5t, center: 0
// B=16, C=256, H=W=128, ks=3, stride=2 -> oH=oW=63
//
// Vectorized: 16 threads per output row, thread k computes outputs j=4k..4k+3
// (thread 15 computes only 3). Input cols 8k..8k+8 per row loaded as
// 2x float4 (32B-aligned) + 1 scalar.

#define C_DIM 256
#define H_DIM 128
#define W_DIM 128
#define OH 63
#define OW 63
#define ROWS_TOTAL (16 * C_DIM * OH)   // 258048

__global__ __launch_bounds__(256) void parab_pool_v2(
    const float* __restrict__ f,
    const float* __restrict__ t,
    float* __restrict__ out)
{
    int tid = blockIdx.x * blockDim.x + threadIdx.x;
    int k   = tid & 15;        // position within the row: 16 threads/row
    int row = tid >> 4;        // global output row = bc*OH + i

    int i  = row % OH;
    int bc = row / OH;
    int c  = bc & (C_DIM - 1);

    const float a  = -t[c];          // corner offset
    const float ha = 0.5f * a;       // edge offset

    const bool full = (k != 15);     // thread 15: only 3 outputs, no col 128

    const float* base = f + ((size_t)(bc * H_DIM + 2 * i)) * W_DIM + 8 * k;

    float r0[9], r1[9], r2[9];
    {
        float4 A = *(const float4*)(base);
        float4 B = *(const float4*)(base + 4);
        r0[0]=A.x; r0[1]=A.y; r0[2]=A.z; r0[3]=A.w;
        r0[4]=B.x; r0[5]=B.y; r0[6]=B.z; r0[7]=B.w;
        r0[8] = full ? base[8] : 0.0f;
    }
    {
        const float* p = base + W_DIM;
        float4 A = *(const float4*)(p);
        float4 B = *(const float4*)(p + 4);
        r1[0]=A.x; r1[1]=A.y; r1[2]=A.z; r1[3]=A.w;
        r1[4]=B.x; r1[5]=B.y; r1[6]=B.z; r1[7]=B.w;
        r1[8] = full ? p[8] : 0.0f;
    }
    {
        const float* p = base + 2 * W_DIM;
        float4 A = *(const float4*)(p);
        float4 B = *(const float4*)(p + 4);
        r2[0]=A.x; r2[1]=A.y; r2[2]=A.z; r2[3]=A.w;
        r2[4]=B.x; r2[5]=B.y; r2[6]=B.z; r2[7]=B.w;
        r2[8] = full ? p[8] : 0.0f;
    }

    float res[4];
    #pragma unroll
    for (int l = 0; l < 4; ++l) {
        const int c0 = 2 * l, c1 = 2 * l + 1, c2 = 2 * l + 2;
        float corners = fmaxf(fmaxf(r0[c0], r0[c2]), fmaxf(r2[c0], r2[c2]));
        float edges   = fmaxf(fmaxf(r0[c1], r2[c1]), fmaxf(r1[c0], r1[c2]));
        res[l] = fmaxf(r1[c1], fmaxf(corners + a, edges + ha));
    }

    float* o = out + (size_t)row * OW + 4 * k;
    o[0] = res[0];
    o[1] = res[1];
    o[2] = res[2];
    if (full) o[3] = res[3];
}

extern "C" void kernel_launch(void* const* d_in, const int* in_sizes, int n_in,
                              void* d_out, int out_size, void* d_ws, size_t ws_size,
                              hipStream_t stream)
{
    const float* f = (const float*)d_in[0];
    const float* t = (const float*)d_in[1];
    float* out = (float*)d_out;

    int total_threads = ROWS_TOTAL * 16;        // 4,128,768
    int block = 256;
    int grid = total_threads / block;           // 16128, exact

    parab_pool_v2<<<grid, block, 0, stream>>>(f, t, out);
}